// Round 4
// baseline (299.154 us; speedup 1.0000x reference)
//
#include <hip/hip_runtime.h>
#include <stdint.h>

// Problem: out[m][n] = sum_k x[m][k] * w[n][k] + bias[n]
//   M=256, N=16384, K=4096, w = dequant(2-bit, group=16 along k)
// Harness dtype universe is {bf16, int32, float32}: fp16 weight_norm arrives as float32.
#define M_DIM 256
#define N_DIM 16384
#define K_DIM 4096
#define BM 128
#define BN 64
#define BK 128
#define NIT (K_DIM / BK)   // 32

typedef __bf16 bf16x8 __attribute__((ext_vector_type(8)));
typedef float  f32x4  __attribute__((ext_vector_type(4)));

// fp32 -> bf16 bits, round-nearest-even (finite inputs)
__device__ __forceinline__ uint32_t f2bf(float f) {
  uint32_t u = __float_as_uint(f);
  return (u + 0x7fffu + ((u >> 16) & 1u)) >> 16;
}

// ---------------------------------------------------------------------------
// Kernel 1: x fp32 [256][4096] -> bf16 fragment-chunk order in workspace.
// Chunk = (m-block of 16 rows) x (k-chunk of 32): 64 slots x 16B.
// Slot L holds row (L&15), k = (L>>4)*8 .. +7  (MFMA 16x16x32 A-frag order).
// ws uint4 index = (mb_glob*128 + kch)*64 + L.
// ---------------------------------------------------------------------------
__global__ __launch_bounds__(256) void cvt_x_kernel(const float* __restrict__ x,
                                                    uint4* __restrict__ ws) {
  int T = blockIdx.x * 256 + threadIdx.x;       // 0..131071
  int mb_glob = T >> 13;                        // 16 m-blocks
  int r       = T & 8191;
  int kch     = r >> 6;                         // 128 k-chunks
  int L       = r & 63;
  int row = mb_glob * 16 + (L & 15);
  int k   = kch * 32 + (L >> 4) * 8;
  const float* p = x + (size_t)row * K_DIM + k;
  float4 a = *(const float4*)p;
  float4 b = *(const float4*)(p + 4);
  uint4 o;
  o.x = f2bf(a.x) | (f2bf(a.y) << 16);
  o.y = f2bf(a.z) | (f2bf(a.w) << 16);
  o.z = f2bf(b.x) | (f2bf(b.y) << 16);
  o.w = f2bf(b.z) | (f2bf(b.w) << 16);
  ws[T] = o;
}

// ---------------------------------------------------------------------------
// Kernel 2: software-pipelined 2-bit dequant + bf16 MFMA GEMM.
// Grid (N/64, M/128), 256 thr (2x2 waves, wave tile 64x32, 16x16x32 MFMA).
// K-loop BK=128, register-prefetch of next iteration's A chunks + q2 + norm
// issued AFTER barrier2 (during compute), consumed BEFORE next barrier1 -> no
// barrier between issue and consume, HBM latency hidden by the MFMA phase.
// Dequant via v_perm 4-entry bf16 LUT: w in {-n, -n/3, +n/3, +n}.
// ---------------------------------------------------------------------------
__global__ __launch_bounds__(256, 2) void gemm2bit_kernel(
    const uint4*    __restrict__ aws,  // A fragment chunks (see cvt)
    const uint32_t* __restrict__ q2,   // [G][4] packed 2-bit (low byte crumbs)
    const float*    __restrict__ nrm,  // [G] group norms (fp32)
    const float*    __restrict__ bias, // [N]
    float*          __restrict__ out)  // [256][16384] fp32
{
  __shared__ uint4 Ab[2048];  // 32 chunks (ts*8+mb) x 64 slots = 32 KiB
  __shared__ uint4 Bb[1024];  // 16 chunks (ts*4+nb) x 64 slots = 16 KiB

  const int tid  = threadIdx.x;
  const int l    = tid & 63;
  const int w    = tid >> 6;
  const int wm   = w >> 1;
  const int wn   = w & 1;
  const int lo4  = l & 15;
  const int qd   = l >> 4;

  const int n0 = blockIdx.x * BN;
  const int m0 = blockIdx.y * BM;

  // B-staging role: thread covers groups (row srow, k-group sgk0 and sgk0+4).
  // srow%8 == l%8 -> ds_write bank-quads cycle with lane: conflict-free.
  // Per row, lanes cover 4 consecutive gidx (64B line) -> coalesced q2 reads.
  const int srow = lo4 + w * 16;       // 0..63 (nb = w)
  const int sgk0 = qd;                 // 0..3
  const int grow = n0 + srow;

  f32x4 acc[4][2];
#pragma unroll
  for (int s = 0; s < 4; ++s)
#pragma unroll
    for (int u = 0; u < 2; ++u)
      acc[s][u] = (f32x4){0.f, 0.f, 0.f, 0.f};

  uint4 pA[8];
  uint4 pQ[2];
  float pN[2];

  const int mrow_base = blockIdx.y * 8;  // global 16-row m-block base

#define LOAD_A(IT)                                                          \
  _Pragma("unroll") for (int j = 0; j < 8; ++j) {                           \
    int s_lin = j * 256 + tid;                                              \
    int c = s_lin >> 6, L = s_lin & 63;                                     \
    pA[j] = aws[((size_t)(mrow_base + (c & 7)) * 128 + (IT)*4 + (c >> 3)) * 64 + L]; \
  }
#define LOAD_B(IT)                                                          \
  _Pragma("unroll") for (int g = 0; g < 2; ++g) {                           \
    int gidx = grow * 256 + (IT)*8 + sgk0 + 4 * g;                          \
    pQ[g] = *(const uint4*)(q2 + (size_t)gidx * 4);                         \
    pN[g] = nrm[gidx];                                                      \
  }

  LOAD_A(0)
  LOAD_B(0)

  for (int it = 0; it < NIT; ++it) {
    // ---- dequant 2 groups from prefetched regs (before barrier1) ----
    uint32_t rw[16];
#pragma unroll
    for (int g = 0; g < 2; ++g) {
      float nv = pN[g];
      uint32_t u3 = f2bf(nv);                    // bf(+n)
      uint32_t u1 = f2bf(nv * 0.33333334f);      // bf(+n/3)
      uint32_t T01 = (u3 | (u1 << 16)) ^ 0x80008000u;  // [-n, -n/3]
      uint32_t T23 = u1 | (u3 << 16);                  // [+n/3, +n]
#pragma unroll
      for (int p = 0; p < 4; ++p) {              // word p -> elements 4p..4p+3
        uint32_t qq = (&pQ[g].x)[p];
        uint32_t v01 = (qq & 3u) | ((qq & 0x0Cu) << 14);
        uint32_t v23 = ((qq >> 4) & 3u) | ((qq & 0xC0u) << 10);
        rw[g * 8 + p * 2]     = __builtin_amdgcn_perm(T23, T01, v01 * 0x0202u + 0x01000100u);
        rw[g * 8 + p * 2 + 1] = __builtin_amdgcn_perm(T23, T01, v23 * 0x0202u + 0x01000100u);
      }
    }

    __syncthreads();  // barrier1: previous compute finished reading LDS

    // ---- A writes: ws is already fragment-ordered -> linear 32 KiB copy ----
#pragma unroll
    for (int j = 0; j < 8; ++j)
      Ab[j * 256 + tid] = pA[j];

    // ---- B writes: group (srow, sgk) -> chunk (sgk>>1)*4 + w, half sgk&1 ----
#pragma unroll
    for (int g = 0; g < 2; ++g) {
      int sgk  = sgk0 + 4 * g;
      int base = ((sgk >> 1) * 4 + w) * 64 + (sgk & 1) * 32 + lo4;
      Bb[base]      = make_uint4(rw[g * 8 + 0], rw[g * 8 + 1], rw[g * 8 + 2], rw[g * 8 + 3]);
      Bb[base + 16] = make_uint4(rw[g * 8 + 4], rw[g * 8 + 5], rw[g * 8 + 6], rw[g * 8 + 7]);
    }

    __syncthreads();  // barrier2: LDS visible

    // ---- prefetch next iteration (issued under the MFMA phase) ----
    if (it + 1 < NIT) {
      LOAD_A(it + 1)
      LOAD_B(it + 1)
    }

    // ---- compute: 4 k-steps of 32; 8 MFMAs per step per wave ----
#pragma unroll
    for (int ts = 0; ts < 4; ++ts) {
      bf16x8 af[4], bf[2];
#pragma unroll
      for (int s = 0; s < 4; ++s)
        af[s] = *(const bf16x8*)&Ab[(ts * 8 + wm * 4 + s) * 64 + l];
#pragma unroll
      for (int u = 0; u < 2; ++u)
        bf[u] = *(const bf16x8*)&Bb[(ts * 4 + wn * 2 + u) * 64 + l];
#pragma unroll
      for (int s = 0; s < 4; ++s)
#pragma unroll
        for (int u = 0; u < 2; ++u)
          acc[s][u] = __builtin_amdgcn_mfma_f32_16x16x32_bf16(
              af[s], bf[u], acc[s][u], 0, 0, 0);
    }
  }
#undef LOAD_A
#undef LOAD_B

  // ---- epilogue: C/D layout col=lane&15 (n), row=(lane>>4)*4+reg (m) ----
  float bv[2];
#pragma unroll
  for (int u = 0; u < 2; ++u)
    bv[u] = bias[n0 + wn * 32 + u * 16 + lo4];

#pragma unroll
  for (int s = 0; s < 4; ++s) {
    int mrow = m0 + wm * 64 + s * 16 + qd * 4;
#pragma unroll
    for (int u = 0; u < 2; ++u) {
      int ncol = n0 + wn * 32 + u * 16 + lo4;
      float* p = out + (size_t)mrow * N_DIM + ncol;
#pragma unroll
      for (int r = 0; r < 4; ++r)
        p[(size_t)r * N_DIM] = acc[s][u][r] + bv[u];
    }
  }
}

// ---------------------------------------------------------------------------
extern "C" void kernel_launch(void* const* d_in, const int* in_sizes, int n_in,
                              void* d_out, int out_size, void* d_ws, size_t ws_size,
                              hipStream_t stream) {
  const float*    x    = (const float*)d_in[0];
  const uint32_t* q2   = (const uint32_t*)d_in[1];
  const float*    nm   = (const float*)d_in[2];
  const float*    bias = (const float*)d_in[3];
  float*          out  = (float*)d_out;
  uint4*          aws  = (uint4*)d_ws;   // 2 MiB: x as bf16 fragment chunks

  cvt_x_kernel<<<512, 256, 0, stream>>>(x, aws);

  dim3 grid(N_DIM / BN, M_DIM / BM);
  gemm2bit_kernel<<<grid, 256, 0, stream>>>(aws, q2, nm, bias, out);
}

// Round 5
// 278.609 us; speedup vs baseline: 1.0737x; 1.0737x over previous
//
#include <hip/hip_runtime.h>
#include <stdint.h>

// Problem: out[m][n] = sum_k x[m][k] * w[n][k] + bias[n]
//   M=256, N=16384, K=4096, w = dequant(2-bit, group=16 along k)
// Harness dtype universe is {bf16, int32, float32}: fp16 weight_norm arrives as float32.
#define M_DIM 256
#define N_DIM 16384
#define K_DIM 4096
#define BM 128
#define BN 64
#define BK 64

typedef __bf16 bf16x8 __attribute__((ext_vector_type(8)));
typedef float  f32x4  __attribute__((ext_vector_type(4)));

// fp32 -> bf16 bits, round-nearest-even (finite inputs)
__device__ __forceinline__ uint32_t f2bf(float f) {
  uint32_t u = __float_as_uint(f);
  return (u + 0x7fffu + ((u >> 16) & 1u)) >> 16;
}

// ---------------------------------------------------------------------------
// Kernel 1: x fp32 [256][4096] -> bf16 fragment-chunk order in workspace.
// Chunk = (m-block of 16 rows) x (k-chunk of 32): 64 slots x 16B.
// Slot L holds row (L&15), k = (L>>4)*8 .. +7  (MFMA 16x16x32 A-frag order).
// ws uint4 index = (mb_glob*128 + kch)*64 + L.
// ---------------------------------------------------------------------------
__global__ __launch_bounds__(256) void cvt_x_kernel(const float* __restrict__ x,
                                                    uint4* __restrict__ ws) {
  int T = blockIdx.x * 256 + threadIdx.x;       // 0..131071
  int mb_glob = T >> 13;                        // 16 m-blocks
  int r       = T & 8191;
  int kch     = r >> 6;                         // 128 k-chunks
  int L       = r & 63;
  int row = mb_glob * 16 + (L & 15);
  int k   = kch * 32 + (L >> 4) * 8;
  const float* p = x + (size_t)row * K_DIM + k;
  float4 a = *(const float4*)p;
  float4 b = *(const float4*)(p + 4);
  uint4 o;
  o.x = f2bf(a.x) | (f2bf(a.y) << 16);
  o.y = f2bf(a.z) | (f2bf(a.w) << 16);
  o.z = f2bf(b.x) | (f2bf(b.y) << 16);
  o.w = f2bf(b.z) | (f2bf(b.w) << 16);
  ws[T] = o;
}

// ---------------------------------------------------------------------------
// Kernel 2: 2-bit dequant + bf16 MFMA GEMM, register-prefetch pipelined.
// Grid (N/64, M/128), 256 thr (2x2 waves, wave tile 64x32, 16x16x32 MFMA).
// R3 skeleton (BK=64, 24 KiB LDS, 0 bank conflicts) + small prefetch state:
// pA[4]+pQ+pN = 21 VGPRs (R4's BK=128 variant spilled: WRITE_SIZE 287 MB).
// Next-iter loads issue after barrier2 (under the MFMA phase), B before A so
// the dequant's vmcnt wait doesn't drain the A loads.
// Dequant: v_perm 4-entry bf16 LUT, w in {-n, -n/3, +n/3, +n}.
// ---------------------------------------------------------------------------
__global__ __launch_bounds__(256, 2) void gemm2bit_kernel(
    const uint4*    __restrict__ aws,  // A fragment chunks (see cvt)
    const uint32_t* __restrict__ q2,   // [G][4] packed 2-bit (low byte crumbs)
    const float*    __restrict__ nrm,  // [G] group norms (fp32)
    const float*    __restrict__ bias, // [N]
    float*          __restrict__ out)  // [256][16384] fp32
{
  __shared__ uint4 Ab[1024];  // 16 chunks (ts*8+mb) x 64 slots = 16 KiB
  __shared__ uint4 Bb[512];   //  8 chunks (ts*4+nb) x 64 slots =  8 KiB

  const int tid  = threadIdx.x;
  const int l    = tid & 63;
  const int w    = tid >> 6;
  const int wm   = w >> 1;
  const int wn   = w & 1;
  const int lo4  = l & 15;
  const int qd   = l >> 4;

  const int n0 = blockIdx.x * BN;
  const int m0 = blockIdx.y * BM;

  // B-staging role: one 16-elem group per thread (64 rows x 4 k-groups)
  const int snb  = tid >> 6;          // n-block 0..3
  const int sqd  = (tid >> 4) & 3;    // k-group within 64 (0..3)
  const int slo4 = tid & 15;          // row within n-block
  const int grow = n0 + snb * 16 + slo4;

  f32x4 acc[4][2];
#pragma unroll
  for (int s = 0; s < 4; ++s)
#pragma unroll
    for (int u = 0; u < 2; ++u)
      acc[s][u] = (f32x4){0.f, 0.f, 0.f, 0.f};

  uint4 pA[4];
  uint4 pQ;
  float pN;

#define LOAD_B(KC)                                              \
  {                                                             \
    int gidx = grow * 256 + ((KC) >> 4) + sqd;                  \
    pQ = *(const uint4*)(q2 + (size_t)gidx * 4);                \
    pN = nrm[gidx];                                             \
  }
#define LOAD_A(KC)                                                            \
  _Pragma("unroll") for (int j = 0; j < 4; ++j) {                             \
    int s_lin = j * 256 + tid;                                                \
    int ca = s_lin >> 6, L = s_lin & 63;                                      \
    pA[j] = aws[((size_t)(blockIdx.y * 8 + (ca & 7)) * 128 + ((KC) >> 5) +    \
                 (ca >> 3)) * 64 + L];                                        \
  }

  LOAD_B(0)
  LOAD_A(0)

  for (int kc = 0; kc < K_DIM; kc += BK) {
    // ---- dequant from prefetched regs (VALU only, before barrier1) ----
    uint32_t rw[8];
    {
      uint32_t u3 = f2bf(pN);                          // bf(+n)
      uint32_t u1 = f2bf(pN * 0.33333334f);            // bf(+n/3)
      uint32_t T01 = (u3 | (u1 << 16)) ^ 0x80008000u;  // bytes: [-n, -n/3]
      uint32_t T23 = u1 | (u3 << 16);                  // bytes: [+n/3, +n]
#pragma unroll
      for (int p = 0; p < 4; ++p) {                    // word p -> elems 4p..4p+3
        uint32_t qq = (&pQ.x)[p];
        uint32_t v01 = (qq & 3u) | ((qq & 0x0Cu) << 14);
        uint32_t v23 = ((qq >> 4) & 3u) | ((qq & 0xC0u) << 10);
        rw[p * 2]     = __builtin_amdgcn_perm(T23, T01, v01 * 0x0202u + 0x01000100u);
        rw[p * 2 + 1] = __builtin_amdgcn_perm(T23, T01, v23 * 0x0202u + 0x01000100u);
      }
    }

    __syncthreads();  // barrier1: previous compute finished reading LDS

    // ---- A writes: ws already fragment-ordered -> linear 16 KiB copy ----
#pragma unroll
    for (int j = 0; j < 4; ++j)
      Ab[j * 256 + tid] = pA[j];

    // ---- B writes: group (row, sqd) -> chunk (sqd>>1)*4 + snb, half sqd&1 ----
    {
      int base = ((sqd >> 1) * 4 + snb) * 64 + (sqd & 1) * 32 + slo4;
      Bb[base]      = make_uint4(rw[0], rw[1], rw[2], rw[3]);  // elems 0..7
      Bb[base + 16] = make_uint4(rw[4], rw[5], rw[6], rw[7]);  // elems 8..15
    }

    __syncthreads();  // barrier2: LDS visible

    // ---- prefetch next iteration (issued under the MFMA phase) ----
    if (kc + BK < K_DIM) {
      LOAD_B(kc + BK)
      LOAD_A(kc + BK)
    }

    // ---- compute: 2 k-steps of 32; 8 MFMAs per step per wave ----
#pragma unroll
    for (int ts = 0; ts < 2; ++ts) {
      bf16x8 af[4], bf[2];
#pragma unroll
      for (int s = 0; s < 4; ++s)
        af[s] = *(const bf16x8*)&Ab[(ts * 8 + wm * 4 + s) * 64 + l];
#pragma unroll
      for (int u = 0; u < 2; ++u)
        bf[u] = *(const bf16x8*)&Bb[(ts * 4 + wn * 2 + u) * 64 + l];
#pragma unroll
      for (int s = 0; s < 4; ++s)
#pragma unroll
        for (int u = 0; u < 2; ++u)
          acc[s][u] = __builtin_amdgcn_mfma_f32_16x16x32_bf16(
              af[s], bf[u], acc[s][u], 0, 0, 0);
    }
  }
#undef LOAD_A
#undef LOAD_B

  // ---- epilogue: C/D layout col=lane&15 (n), row=(lane>>4)*4+reg (m) ----
  float bv[2];
#pragma unroll
  for (int u = 0; u < 2; ++u)
    bv[u] = bias[n0 + wn * 32 + u * 16 + lo4];

#pragma unroll
  for (int s = 0; s < 4; ++s) {
    int mrow = m0 + wm * 64 + s * 16 + qd * 4;
#pragma unroll
    for (int u = 0; u < 2; ++u) {
      int ncol = n0 + wn * 32 + u * 16 + lo4;
      float* p = out + (size_t)mrow * N_DIM + ncol;
#pragma unroll
      for (int r = 0; r < 4; ++r)
        p[(size_t)r * N_DIM] = acc[s][u][r] + bv[u];
    }
  }
}

// ---------------------------------------------------------------------------
extern "C" void kernel_launch(void* const* d_in, const int* in_sizes, int n_in,
                              void* d_out, int out_size, void* d_ws, size_t ws_size,
                              hipStream_t stream) {
  const float*    x    = (const float*)d_in[0];
  const uint32_t* q2   = (const uint32_t*)d_in[1];
  const float*    nm   = (const float*)d_in[2];
  const float*    bias = (const float*)d_in[3];
  float*          out  = (float*)d_out;
  uint4*          aws  = (uint4*)d_ws;   // 2 MiB: x as bf16 fragment chunks

  cvt_x_kernel<<<512, 256, 0, stream>>>(x, aws);

  dim3 grid(N_DIM / BN, M_DIM / BM);
  gemm2bit_kernel<<<grid, 256, 0, stream>>>(aws, q2, nm, bias, out);
}

// Round 6
// 180.290 us; speedup vs baseline: 1.6593x; 1.5453x over previous
//
#include <hip/hip_runtime.h>
#include <stdint.h>

// Problem: out[m][n] = sum_k x[m][k] * w[n][k] + bias[n]
//   M=256, N=16384, K=4096, w = dequant(2-bit, group=16 along k)
// Harness dtype universe is {bf16, int32, float32}: fp16 weight_norm arrives as float32.
//
// History (keep!):
//  R3: BK=64 skeleton, fmaf dequant, 2 blocks/CU -> 92 us, nothing saturated (chain-bound).
//  R4/R5: register prefetch across __syncthreads -> compiler scratch traffic
//         (WRITE_SIZE 16->190 MB). DO NOT keep arrays live across barriers.
//  R6: K-split=2 (chain 64->32 iters, 4 blocks/CU) + v_perm LUT dequant.
#define M_DIM 256
#define N_DIM 16384
#define K_DIM 4096
#define BM 128
#define BN 64
#define BK 64
#define KSPLIT 2
#define KSLICE (K_DIM / KSPLIT)   // 2048

typedef __bf16 bf16x8 __attribute__((ext_vector_type(8)));
typedef float  f32x4  __attribute__((ext_vector_type(4)));

// fp32 -> bf16 bits, round-nearest-even (finite inputs)
__device__ __forceinline__ uint32_t f2bf(float f) {
  uint32_t u = __float_as_uint(f);
  return (u + 0x7fffu + ((u >> 16) & 1u)) >> 16;
}

// ---------------------------------------------------------------------------
// Kernel 1: x fp32 [256][4096] -> bf16 fragment-chunk order in workspace.
// Chunk = (m-block of 16 rows) x (k-chunk of 32): 64 slots x 16B.
// Slot L holds row (L&15), k = (L>>4)*8 .. +7  (MFMA 16x16x32 A-frag order).
// ws uint4 index = (mb_glob*128 + kch)*64 + L.
// ---------------------------------------------------------------------------
__global__ __launch_bounds__(256) void cvt_x_kernel(const float* __restrict__ x,
                                                    uint4* __restrict__ ws) {
  int T = blockIdx.x * 256 + threadIdx.x;       // 0..131071
  int mb_glob = T >> 13;                        // 16 m-blocks
  int r       = T & 8191;
  int kch     = r >> 6;                         // 128 k-chunks
  int L       = r & 63;
  int row = mb_glob * 16 + (L & 15);
  int k   = kch * 32 + (L >> 4) * 8;
  const float* p = x + (size_t)row * K_DIM + k;
  float4 a = *(const float4*)p;
  float4 b = *(const float4*)(p + 4);
  uint4 o;
  o.x = f2bf(a.x) | (f2bf(a.y) << 16);
  o.y = f2bf(a.z) | (f2bf(a.w) << 16);
  o.z = f2bf(b.x) | (f2bf(b.y) << 16);
  o.w = f2bf(b.z) | (f2bf(b.w) << 16);
  ws[T] = o;
}

// ---------------------------------------------------------------------------
// Kernel 2: 2-bit dequant + bf16 MFMA GEMM, K-split=2.
// Grid (N/64, M/128, 2), 256 thr (2x2 waves, wave tile 64x32, 16x16x32 MFMA).
// R3 skeleton: no state lives across barriers (R4/R5 spill lesson).
// Dequant: v_perm 4-entry bf16 LUT, w in {-n, -n/3, +n/3, +n}.
// k-halves combine via fp32 atomicAdd onto memset-zeroed out (2 blocks/line).
// ---------------------------------------------------------------------------
__global__ __launch_bounds__(256, 4) void gemm2bit_kernel(
    const uint4*    __restrict__ aws,  // A fragment chunks (see cvt)
    const uint32_t* __restrict__ q2,   // [G][4] packed 2-bit (low byte crumbs)
    const float*    __restrict__ nrm,  // [G] group norms (fp32)
    const float*    __restrict__ bias, // [N]
    float*          __restrict__ out)  // [256][16384] fp32, pre-zeroed
{
  __shared__ uint4 Ab[1024];  // 16 chunks (ts*8+mb) x 64 slots = 16 KiB
  __shared__ uint4 Bb[512];   //  8 chunks (ts*4+nb) x 64 slots =  8 KiB

  const int tid  = threadIdx.x;
  const int l    = tid & 63;
  const int w    = tid >> 6;
  const int wm   = w >> 1;
  const int wn   = w & 1;
  const int lo4  = l & 15;
  const int qd   = l >> 4;

  const int n0    = blockIdx.x * BN;
  const int m0    = blockIdx.y * BM;
  const int kbase = blockIdx.z * KSLICE;

  // B-staging role: one 16-elem group per thread (64 rows x 4 k-groups)
  const int snb  = tid >> 6;          // n-block 0..3
  const int sqd  = (tid >> 4) & 3;    // k-group within 64 (0..3)
  const int slo4 = tid & 15;          // row within n-block
  const int grow = n0 + snb * 16 + slo4;

  f32x4 acc[4][2];
#pragma unroll
  for (int s = 0; s < 4; ++s)
#pragma unroll
    for (int u = 0; u < 2; ++u)
      acc[s][u] = (f32x4){0.f, 0.f, 0.f, 0.f};

  for (int kc = kbase; kc < kbase + KSLICE; kc += BK) {
    __syncthreads();  // previous compute finished reading LDS

    // ---- A staging: coalesced uint4 load from chunk-ordered ws -> LDS ----
#pragma unroll
    for (int j = 0; j < 4; ++j) {
      int s_lin = j * 256 + tid;          // 0..1023
      int ca = s_lin >> 6;                // chunk = ts*8 + mb
      int L  = s_lin & 63;
      uint4 g = aws[((size_t)(blockIdx.y * 8 + (ca & 7)) * 128 + (kc >> 5) +
                     (ca >> 3)) * 64 + L];
      Ab[ca * 64 + L] = g;
    }

    // ---- B staging: load group, v_perm LUT dequant, 2x ds_write_b128 ----
    {
      int gidx = grow * 256 + (kc >> 4) + sqd;
      uint4 q  = *(const uint4*)(q2 + (size_t)gidx * 4);
      float nv = nrm[gidx];
      uint32_t u3 = f2bf(nv);                          // bf(+n)
      uint32_t u1 = f2bf(nv * 0.33333334f);            // bf(+n/3)
      uint32_t T01 = (u3 | (u1 << 16)) ^ 0x80008000u;  // bytes: [-n, -n/3]
      uint32_t T23 = u1 | (u3 << 16);                  // bytes: [+n/3, +n]
      uint32_t rw[8];
#pragma unroll
      for (int p = 0; p < 4; ++p) {                    // word p -> elems 4p..4p+3
        uint32_t qq = (&q.x)[p];
        uint32_t v01 = (qq & 3u) | ((qq & 0x0Cu) << 14);
        uint32_t v23 = ((qq >> 4) & 3u) | ((qq & 0xC0u) << 10);
        rw[p * 2]     = __builtin_amdgcn_perm(T23, T01, v01 * 0x0202u + 0x01000100u);
        rw[p * 2 + 1] = __builtin_amdgcn_perm(T23, T01, v23 * 0x0202u + 0x01000100u);
      }
      // group (row, sqd) -> chunk (sqd>>1)*4 + snb, half sqd&1
      int base = ((sqd >> 1) * 4 + snb) * 64 + (sqd & 1) * 32 + slo4;
      Bb[base]      = make_uint4(rw[0], rw[1], rw[2], rw[3]);  // elems 0..7
      Bb[base + 16] = make_uint4(rw[4], rw[5], rw[6], rw[7]);  // elems 8..15
    }

    __syncthreads();  // LDS visible

    // ---- compute: 2 k-steps of 32; 8 MFMAs per step per wave ----
#pragma unroll
    for (int ts = 0; ts < 2; ++ts) {
      bf16x8 af[4], bf[2];
#pragma unroll
      for (int s = 0; s < 4; ++s)
        af[s] = *(const bf16x8*)&Ab[(ts * 8 + wm * 4 + s) * 64 + l];
#pragma unroll
      for (int u = 0; u < 2; ++u)
        bf[u] = *(const bf16x8*)&Bb[(ts * 4 + wn * 2 + u) * 64 + l];
#pragma unroll
      for (int s = 0; s < 4; ++s)
#pragma unroll
        for (int u = 0; u < 2; ++u)
          acc[s][u] = __builtin_amdgcn_mfma_f32_16x16x32_bf16(
              af[s], bf[u], acc[s][u], 0, 0, 0);
    }
  }

  // ---- epilogue: C/D layout col=lane&15 (n), row=(lane>>4)*4+reg (m) ----
  float bv[2];
#pragma unroll
  for (int u = 0; u < 2; ++u)
    bv[u] = (blockIdx.z == 0) ? bias[n0 + wn * 32 + u * 16 + lo4] : 0.0f;

#pragma unroll
  for (int s = 0; s < 4; ++s) {
    int mrow = m0 + wm * 64 + s * 16 + qd * 4;
#pragma unroll
    for (int u = 0; u < 2; ++u) {
      int ncol = n0 + wn * 32 + u * 16 + lo4;
      float* p = out + (size_t)mrow * N_DIM + ncol;
#pragma unroll
      for (int r = 0; r < 4; ++r)
        atomicAdd(p + (size_t)r * N_DIM, acc[s][u][r] + bv[u]);
    }
  }
}

// ---------------------------------------------------------------------------
extern "C" void kernel_launch(void* const* d_in, const int* in_sizes, int n_in,
                              void* d_out, int out_size, void* d_ws, size_t ws_size,
                              hipStream_t stream) {
  const float*    x    = (const float*)d_in[0];
  const uint32_t* q2   = (const uint32_t*)d_in[1];
  const float*    nm   = (const float*)d_in[2];
  const float*    bias = (const float*)d_in[3];
  float*          out  = (float*)d_out;
  uint4*          aws  = (uint4*)d_ws;   // 2 MiB: x as bf16 fragment chunks

  // zero output: k-split halves accumulate via atomicAdd
  hipMemsetAsync(d_out, 0, (size_t)out_size * sizeof(float), stream);

  cvt_x_kernel<<<512, 256, 0, stream>>>(x, aws);

  dim3 grid(N_DIM / BN, M_DIM / BM, KSPLIT);
  gemm2bit_kernel<<<grid, 256, 0, stream>>>(aws, q2, nm, bias, out);
}